// Round 1
// baseline (986.489 us; speedup 1.0000x reference)
//
#include <hip/hip_runtime.h>
#include <stdint.h>

// GATv2 self-attention, MI355X/gfx950.
// B=256 S=8 F=2048 H=8. fp32 in/out; GEMMs via bf16 hi/lo 3-pass MFMA (fp32-accurate).
//
// Pipeline:
//  1. split_x:        X fp32 -> Xhi/Xlo bf16 planes            (16 MB streamed)
//  2. transpose_w:    W [h][c][f] fp32 -> Whi/Wlo [h][f][c]    (268 MB streamed, LDS-tiled transpose)
//  3. gemm1:          proj0[b, h*F+f] = X[b,0,:]·W1            (M=256  K=2048 N=16384)
//  4. gemm2:          Wh = leaky(proj0 + X[b,s,:]·W2)          (M=2048 K=2048 N=16384)  <- dominant
//  5. esoftmax:       e[b,h,s] = Wh·att_w ; softmax over s=8
//  6. out:            out = x + (1/8)Σ_h (attn*Wh + bias)

typedef __attribute__((ext_vector_type(4))) float f32x4;
typedef __attribute__((ext_vector_type(8))) short bf16x8;
typedef __attribute__((ext_vector_type(4))) unsigned short u16x4;
typedef unsigned short u16;
typedef unsigned int u32;

#define LRELU_ALPHA 0.3f

__device__ __forceinline__ u16 bf16_rn(float x) {
  u32 u = __float_as_uint(x);
  u32 r = 0x7FFFu + ((u >> 16) & 1u);
  return (u16)((u + r) >> 16);
}
__device__ __forceinline__ float bf16_to_f32(u16 h) {
  return __uint_as_float(((u32)h) << 16);
}

// -------------------- prep: X fp32 -> hi/lo bf16 --------------------
__global__ __launch_bounds__(256) void split_x_kernel(
    const float* __restrict__ X, u16* __restrict__ Xhi, u16* __restrict__ Xlo) {
  int idx = (blockIdx.x * 256 + threadIdx.x) * 4;
  f32x4 v = *(const f32x4*)&X[idx];
  u16x4 hi, lo;
#pragma unroll
  for (int j = 0; j < 4; ++j) {
    u16 h = bf16_rn(v[j]);
    hi[j] = h;
    lo[j] = bf16_rn(v[j] - bf16_to_f32(h));
  }
  *(u16x4*)&Xhi[idx] = hi;
  *(u16x4*)&Xlo[idx] = lo;
}

// ---------- prep: W [h][c=4096][f=2048] fp32 -> [h][f][c] hi/lo bf16 ----------
__global__ __launch_bounds__(256) void transpose_split_w(
    const float* __restrict__ W, u16* __restrict__ Whi, u16* __restrict__ Wlo) {
  __shared__ float tile[64][65];  // +1 pad: conflict-free transposed reads
  int bid = blockIdx.x;
  int h = bid >> 11;       // 2048 tiles per head
  int t = bid & 2047;
  int ct = t & 63;         // 64 tiles along c (4096)
  int ft = t >> 6;         // 32 tiles along f (2048)
  int c0 = ct << 6, f0 = ft << 6;
  int tid = threadIdx.x;
  int rr = tid >> 4;             // 0..15
  int q4 = (tid & 15) << 2;      // 0,4,..,60
  const float* src = W + (size_t)(h * 4096 + c0) * 2048 + f0;
#pragma unroll
  for (int it = 0; it < 4; ++it) {
    int r = it * 16 + rr;        // c-local
    f32x4 v = *(const f32x4*)&src[(size_t)r * 2048 + q4];
    tile[r][q4] = v[0]; tile[r][q4 + 1] = v[1];
    tile[r][q4 + 2] = v[2]; tile[r][q4 + 3] = v[3];
  }
  __syncthreads();
  size_t dst = (size_t)(h * 2048 + f0) * 4096 + c0;
#pragma unroll
  for (int it = 0; it < 4; ++it) {
    int fr = it * 16 + rr;       // f-local
    u16x4 hi, lo;
#pragma unroll
    for (int j = 0; j < 4; ++j) {
      float a = tile[q4 + j][fr];
      u16 hb = bf16_rn(a);
      hi[j] = hb;
      lo[j] = bf16_rn(a - bf16_to_f32(hb));
    }
    *(u16x4*)&Whi[dst + (size_t)fr * 4096 + q4] = hi;
    *(u16x4*)&Wlo[dst + (size_t)fr * 4096 + q4] = lo;
  }
}

// -------------------- GEMM: 128x128 tile, BK=32, bf16x3 MFMA --------------------
__device__ __forceinline__ void gl_lds16(const u16* g, u16* l) {
  __builtin_amdgcn_global_load_lds(
      (const __attribute__((address_space(1))) void*)g,
      (__attribute__((address_space(3))) void*)l, 16, 0, 0);
}

// A: [M][K] bf16 planes, row stride AST elements (X hi/lo).
// B: [N][4096] bf16 planes (transposed W), k offset koff (0 -> W1, 2048 -> W2).
// C: fp32 [M][16384]. EPI2 adds proj0 (broadcast over s) + LeakyReLU.
template <int AST, bool EPI2>
__global__ __launch_bounds__(256) void gemm_split3(
    const u16* __restrict__ Ahi, const u16* __restrict__ Alo,
    const u16* __restrict__ Bhi, const u16* __restrict__ Blo,
    const float* __restrict__ proj0, float* __restrict__ C,
    int Mdim, int koff) {
  __shared__ alignas(16) u16 lAhi[128 * 32];
  __shared__ alignas(16) u16 lAlo[128 * 32];
  __shared__ alignas(16) u16 lBhi[128 * 32];
  __shared__ alignas(16) u16 lBlo[128 * 32];

  int tid = threadIdx.x;
  int lane = tid & 63;
  int w = tid >> 6;

  // XCD-bijective swizzle (nwg % 8 == 0 for both grids); mt-major within nt so
  // consecutive blocks on one XCD share a B panel.
  int nwg = gridDim.x;
  int bid = blockIdx.x;
  int wg = (bid & 7) * (nwg >> 3) + (bid >> 3);
  int MT = Mdim >> 7;
  int nt = wg / MT;
  int mt = wg - nt * MT;
  int m0 = mt << 7, n0 = nt << 7;

  // staging: plane = [128 rows][32 bf16] = 8 KB = 8 chunks of 1 KB; wave w owns
  // chunks {2w, 2w+1}; lane l -> row l>>2, 16B-unit l&3 within chunk (linear LDS).
  // XOR swizzle (unit ^= row&3) applied on the GLOBAL source (rule 21).
  int srow = lane >> 2;
  int sunit = lane & 3;
  int r0 = w * 32 + srow;
  int r1 = r0 + 16;
  size_t qc0 = (size_t)((sunit ^ (r0 & 3)) << 3);
  size_t qc1 = (size_t)((sunit ^ (r1 & 3)) << 3);
  size_t offA0 = (size_t)(m0 + r0) * AST + qc0;
  size_t offA1 = (size_t)(m0 + r1) * AST + qc1;
  size_t offB0 = (size_t)(n0 + r0) * 4096 + (size_t)koff + qc0;
  size_t offB1 = (size_t)(n0 + r1) * 4096 + (size_t)koff + qc1;
  const int lds0 = w * 1024;       // u16 index: chunk(2w)*512
  const int lds1 = lds0 + 512;

  f32x4 acc[4][4];
#pragma unroll
  for (int i = 0; i < 4; ++i)
#pragma unroll
    for (int j = 0; j < 4; ++j) acc[i][j] = (f32x4){0.f, 0.f, 0.f, 0.f};

  const int wr = w >> 1, wc = w & 1;   // 2x2 waves -> 64x64 per wave
  const int frow = lane & 15;
  const int kgrp = lane >> 4;

  // LDS frag read indices (u16): row*32 + ((kgrp ^ (row&3))*8)  [un-swizzle]
  int aidx[4], bidx[4];
#pragma unroll
  for (int i = 0; i < 4; ++i) {
    int ar = wr * 64 + i * 16 + frow;
    aidx[i] = ar * 32 + ((kgrp ^ (ar & 3)) << 3);
    int br = wc * 64 + i * 16 + frow;
    bidx[i] = br * 32 + ((kgrp ^ (br & 3)) << 3);
  }

  for (int kt = 0; kt < 64; ++kt) {
    size_t ko = (size_t)kt * 32;
    gl_lds16(Ahi + offA0 + ko, &lAhi[lds0]);
    gl_lds16(Ahi + offA1 + ko, &lAhi[lds1]);
    gl_lds16(Alo + offA0 + ko, &lAlo[lds0]);
    gl_lds16(Alo + offA1 + ko, &lAlo[lds1]);
    gl_lds16(Bhi + offB0 + ko, &lBhi[lds0]);
    gl_lds16(Bhi + offB1 + ko, &lBhi[lds1]);
    gl_lds16(Blo + offB0 + ko, &lBlo[lds0]);
    gl_lds16(Blo + offB1 + ko, &lBlo[lds1]);
    __syncthreads();

    bf16x8 ah[4], al[4], bh[4], bl[4];
#pragma unroll
    for (int i = 0; i < 4; ++i) {
      ah[i] = *(const bf16x8*)&lAhi[aidx[i]];
      al[i] = *(const bf16x8*)&lAlo[aidx[i]];
      bh[i] = *(const bf16x8*)&lBhi[bidx[i]];
      bl[i] = *(const bf16x8*)&lBlo[bidx[i]];
    }
#pragma unroll
    for (int i = 0; i < 4; ++i)
#pragma unroll
      for (int j = 0; j < 4; ++j) {
        acc[i][j] = __builtin_amdgcn_mfma_f32_16x16x32_bf16(ah[i], bh[j], acc[i][j], 0, 0, 0);
        acc[i][j] = __builtin_amdgcn_mfma_f32_16x16x32_bf16(ah[i], bl[j], acc[i][j], 0, 0, 0);
        acc[i][j] = __builtin_amdgcn_mfma_f32_16x16x32_bf16(al[i], bh[j], acc[i][j], 0, 0, 0);
      }
    __syncthreads();
  }

  // epilogue: C/D layout col=lane&15, row=(lane>>4)*4+reg  [m89-verified]
#pragma unroll
  for (int i = 0; i < 4; ++i) {
    int gmb = m0 + wr * 64 + i * 16 + kgrp * 4;
#pragma unroll
    for (int j = 0; j < 4; ++j) {
      int gn = n0 + wc * 64 + j * 16 + frow;
#pragma unroll
      for (int r = 0; r < 4; ++r) {
        float v = acc[i][j][r];
        int gm = gmb + r;
        if constexpr (EPI2) {
          v += proj0[(size_t)(gm >> 3) * 16384 + gn];  // b = gm>>3
          v = v > 0.f ? v : v * LRELU_ALPHA;
        }
        C[(size_t)gm * 16384 + gn] = v;
      }
    }
  }
}

// -------------------- e = Wh·att_w ; softmax over s (8) --------------------
__global__ __launch_bounds__(256) void esoftmax_kernel(
    const float* __restrict__ Wh, const float* __restrict__ att_w,
    float* __restrict__ attn) {
  int bid = blockIdx.x;          // B*H = 2048 blocks
  int b = bid >> 3, h = bid & 7;
  int tid = threadIdx.x, lane = tid & 63, w = tid >> 6;
  __shared__ float ev[8];
  const float* aw = att_w + h * 2048;
#pragma unroll
  for (int si = 0; si < 2; ++si) {
    int s = w * 2 + si;
    const float* row = Wh + (size_t)((b * 8 + s) * 8 + h) * 2048;
    float sum = 0.f;
#pragma unroll
    for (int i = 0; i < 8; ++i) {
      int idx = (i * 64 + lane) * 4;
      f32x4 rv = *(const f32x4*)&row[idx];
      f32x4 av = *(const f32x4*)&aw[idx];
      sum += rv[0] * av[0] + rv[1] * av[1] + rv[2] * av[2] + rv[3] * av[3];
    }
#pragma unroll
    for (int off = 32; off > 0; off >>= 1) sum += __shfl_down(sum, off, 64);
    if (lane == 0) ev[s] = sum;
  }
  __syncthreads();
  if (tid == 0) {
    float mx = ev[0];
#pragma unroll
    for (int s = 1; s < 8; ++s) mx = fmaxf(mx, ev[s]);
    float ex[8], den = 0.f;
#pragma unroll
    for (int s = 0; s < 8; ++s) { ex[s] = expf(ev[s] - mx); den += ex[s]; }
    float inv = 1.f / den;
#pragma unroll
    for (int s = 0; s < 8; ++s) attn[b * 64 + h * 8 + s] = ex[s] * inv;
  }
}

// -------------------- out = x + (1/8) Σ_h (attn*Wh + bias) --------------------
__global__ __launch_bounds__(256) void out_kernel(
    const float* __restrict__ X, const float* __restrict__ bias,
    const float* __restrict__ Wh, const float* __restrict__ attn,
    float* __restrict__ out) {
  int bid = blockIdx.x;          // 2048 rows x 2 halves
  int m = bid >> 1;
  int half = bid & 1;
  int b = m >> 3, s = m & 7;
  int f0 = half * 1024 + threadIdx.x * 4;
  __shared__ float a_sm[8];
  if (threadIdx.x < 8) a_sm[threadIdx.x] = attn[b * 64 + threadIdx.x * 8 + s];
  __syncthreads();
  f32x4 acc = *(const f32x4*)&X[(size_t)m * 2048 + f0];
  f32x4 hs = {0.f, 0.f, 0.f, 0.f};
#pragma unroll
  for (int h = 0; h < 8; ++h) {
    f32x4 wv = *(const f32x4*)&Wh[(size_t)m * 16384 + h * 2048 + f0];
    f32x4 bv = *(const f32x4*)&bias[h * 2048 + f0];
    hs += wv * a_sm[h] + bv;
  }
  acc += hs * 0.125f;
  *(f32x4*)&out[(size_t)m * 2048 + f0] = acc;
}

extern "C" void kernel_launch(void* const* d_in, const int* in_sizes, int n_in,
                              void* d_out, int out_size, void* d_ws, size_t ws_size,
                              hipStream_t stream) {
  const float* X = (const float*)d_in[0];       // [256][8][2048]
  const float* W = (const float*)d_in[1];       // [8][4096][2048]
  const float* att_w = (const float*)d_in[2];   // [8][2048]
  const float* bias = (const float*)d_in[3];    // [8][2048]
  float* out = (float*)d_out;

  char* ws = (char*)d_ws;                       // 436,273,152 B used
  u16* Whi = (u16*)ws;                          // 134,217,728
  u16* Wlo = (u16*)(ws + 134217728ull);         // 134,217,728
  u16* Xhi = (u16*)(ws + 268435456ull);         //   8,388,608
  u16* Xlo = (u16*)(ws + 276824064ull);         //   8,388,608
  float* proj0 = (float*)(ws + 285212672ull);   //  16,777,216  [256][16384]
  float* Wh = (float*)(ws + 301989888ull);      // 134,217,728  [2048][16384]
  float* attn = (float*)(ws + 436207616ull);    //      65,536  [256][8][8]

  split_x_kernel<<<4096, 256, 0, stream>>>(X, Xhi, Xlo);
  transpose_split_w<<<16384, 256, 0, stream>>>(W, Whi, Wlo);
  // GEMM1: rows are X[b,0,:] -> A row stride = 8*2048, M=256, k offset 0 (W1)
  gemm_split3<16384, false><<<256, 256, 0, stream>>>(Xhi, Xlo, Whi, Wlo, nullptr, proj0, 256, 0);
  // GEMM2: all (b,s) rows -> stride 2048, M=2048, k offset 2048 (W2)
  gemm_split3<2048, true><<<2048, 256, 0, stream>>>(Xhi, Xlo, Whi, Wlo, proj0, Wh, 2048, 2048);
  esoftmax_kernel<<<2048, 256, 0, stream>>>(Wh, att_w, attn);
  out_kernel<<<4096, 256, 0, stream>>>(X, bias, Wh, attn, out);
}

// Round 2
// 966.105 us; speedup vs baseline: 1.0211x; 1.0211x over previous
//
#include <hip/hip_runtime.h>
#include <stdint.h>

// GATv2 self-attention, MI355X/gfx950.
// B=256 S=8 F=2048 H=8. fp32 in/out; GEMMs via bf16 hi/lo 3-pass MFMA (fp32-accurate).
//
// Pipeline:
//  1. split_x:        X fp32 -> Xhi/Xlo bf16 planes            (16 MB streamed)
//  2. transpose_w:    W [h][c][f] fp32 -> Whi/Wlo [h][f][c]    (268 MB streamed, LDS-tiled transpose)
//  3. gemm3p<...,false>: proj0[b, h*F+f] = X[b,0,:]·W1         (M=256  K=2048 N=16384)
//  4. gemm3p<...,true>:  Wh = leaky(proj0 + X[b,s,:]·W2)       (M=2048 K=2048 N=16384)  <- dominant
//  5. esoftmax:       e[b,h,s] = Wh·att_w ; softmax over s=8
//  6. out:            out = x + (1/8)SUM_h (attn*Wh + bias)
//
// GEMM structure (this round): 256x256 tile, BK=32, 8 waves (2Mx4N), 3 phases per
// K-tile (hh/hl/lh), raw s_barrier + counted vmcnt(4) (T3/T4), bank-conflict-free
// swizzle: phys 16B-unit = (kgrp + (row>>1)) & 3 (T2), setprio around MFMA (T5).

typedef __attribute__((ext_vector_type(4))) float f32x4;
typedef __attribute__((ext_vector_type(8))) short bf16x8;
typedef __attribute__((ext_vector_type(4))) unsigned short u16x4;
typedef unsigned short u16;
typedef unsigned int u32;

#define LRELU_ALPHA 0.3f

__device__ __forceinline__ u16 bf16_rn(float x) {
  u32 u = __float_as_uint(x);
  u32 r = 0x7FFFu + ((u >> 16) & 1u);
  return (u16)((u + r) >> 16);
}
__device__ __forceinline__ float bf16_to_f32(u16 h) {
  return __uint_as_float(((u32)h) << 16);
}

// -------------------- prep: X fp32 -> hi/lo bf16 --------------------
__global__ __launch_bounds__(256) void split_x_kernel(
    const float* __restrict__ X, u16* __restrict__ Xhi, u16* __restrict__ Xlo) {
  int idx = (blockIdx.x * 256 + threadIdx.x) * 4;
  f32x4 v = *(const f32x4*)&X[idx];
  u16x4 hi, lo;
#pragma unroll
  for (int j = 0; j < 4; ++j) {
    u16 h = bf16_rn(v[j]);
    hi[j] = h;
    lo[j] = bf16_rn(v[j] - bf16_to_f32(h));
  }
  *(u16x4*)&Xhi[idx] = hi;
  *(u16x4*)&Xlo[idx] = lo;
}

// ---------- prep: W [h][c=4096][f=2048] fp32 -> [h][f][c] hi/lo bf16 ----------
__global__ __launch_bounds__(256) void transpose_split_w(
    const float* __restrict__ W, u16* __restrict__ Whi, u16* __restrict__ Wlo) {
  __shared__ float tile[64][65];  // +1 pad: conflict-free transposed reads
  int bid = blockIdx.x;
  int h = bid >> 11;       // 2048 tiles per head
  int t = bid & 2047;
  int ct = t & 63;         // 64 tiles along c (4096)
  int ft = t >> 6;         // 32 tiles along f (2048)
  int c0 = ct << 6, f0 = ft << 6;
  int tid = threadIdx.x;
  int rr = tid >> 4;             // 0..15
  int q4 = (tid & 15) << 2;      // 0,4,..,60
  const float* src = W + (size_t)(h * 4096 + c0) * 2048 + f0;
#pragma unroll
  for (int it = 0; it < 4; ++it) {
    int r = it * 16 + rr;        // c-local
    f32x4 v = *(const f32x4*)&src[(size_t)r * 2048 + q4];
    tile[r][q4] = v[0]; tile[r][q4 + 1] = v[1];
    tile[r][q4 + 2] = v[2]; tile[r][q4 + 3] = v[3];
  }
  __syncthreads();
  size_t dst = (size_t)(h * 2048 + f0) * 4096 + c0;
#pragma unroll
  for (int it = 0; it < 4; ++it) {
    int fr = it * 16 + rr;       // f-local
    u16x4 hi, lo;
#pragma unroll
    for (int j = 0; j < 4; ++j) {
      float a = tile[q4 + j][fr];
      u16 hb = bf16_rn(a);
      hi[j] = hb;
      lo[j] = bf16_rn(a - bf16_to_f32(hb));
    }
    *(u16x4*)&Whi[dst + (size_t)fr * 4096 + q4] = hi;
    *(u16x4*)&Wlo[dst + (size_t)fr * 4096 + q4] = lo;
  }
}

// -------------------- GEMM: 256x256 tile, BK=32, 3-phase hi/lo schedule --------------------
__device__ __forceinline__ void gl_lds16(const u16* g, u16* l) {
  __builtin_amdgcn_global_load_lds(
      (const __attribute__((address_space(1))) void*)g,
      (__attribute__((address_space(3))) void*)l, 16, 0, 0);
}

#define BAR()    asm volatile("s_barrier" ::: "memory")
#define VM4BAR() asm volatile("s_waitcnt vmcnt(4)\n\ts_barrier" ::: "memory")
#define VM0BAR() asm volatile("s_waitcnt vmcnt(0)\n\ts_barrier" ::: "memory")

// A: [M][AST] bf16 planes (X hi/lo). B: [N][4096] bf16 planes (transposed W),
// k offset koff (0 -> W1, 2048 -> W2). C: fp32 [M][16384].
// EPI2: C = leaky(acc + proj0[b (=gm>>3)][gn]).
template <int AST, bool EPI2>
__global__ __launch_bounds__(512, 2) void gemm3p(
    const u16* __restrict__ Ahi, const u16* __restrict__ Alo,
    const u16* __restrict__ Bhi, const u16* __restrict__ Blo,
    const float* __restrict__ proj0, float* __restrict__ C,
    int Mdim, int koff) {
  // 4 arrays x 2 bufs x (256 rows x 32 u16) = 128 KiB
  __shared__ alignas(16) u16 lAh[2][8192];
  __shared__ alignas(16) u16 lAl[2][8192];
  __shared__ alignas(16) u16 lBh[2][8192];
  __shared__ alignas(16) u16 lBl[2][8192];

  const int tid = threadIdx.x;
  const int lane = tid & 63;
  const int w = tid >> 6;

  // XCD-bijective swizzle (grids are multiples of 8); mt-major within nt.
  const int nwg = gridDim.x;
  const int bid = blockIdx.x;
  const int wg = (bid & 7) * (nwg >> 3) + (bid >> 3);
  const int MT = Mdim >> 8;
  const int nt = wg / MT;
  const int mt = wg - nt * MT;
  const int m0 = mt << 8, n0 = nt << 8;

  // ---- staging geometry: each array = 16 chunks of 1 KiB (16 rows x 64 B).
  // wave w owns chunks {2w, 2w+1}. gl_lds writes linearly: lane l -> row
  // c*16 + (l>>2), physical 16B-unit l&3. LDS swizzle: phys_unit =
  // (log_unit + (row>>1)) & 3  -> source fetches log_unit = (l&3) - (row>>1).
  const int c0i = 2 * w, c1i = 2 * w + 1;
  const int r0 = c0i * 16 + (lane >> 2);
  const int r1 = c1i * 16 + (lane >> 2);
  const int ul0 = ((lane & 3) - (r0 >> 1)) & 3;
  const int ul1 = ((lane & 3) - (r1 >> 1)) & 3;
  const size_t sA0 = (size_t)(m0 + r0) * AST + ul0 * 8;
  const size_t sA1 = (size_t)(m0 + r1) * AST + ul1 * 8;
  const size_t sB0 = (size_t)(n0 + r0) * 4096 + (size_t)koff + ul0 * 8;
  const size_t sB1 = (size_t)(n0 + r1) * 4096 + (size_t)koff + ul1 * 8;
  const int cw0 = c0i * 512, cw1 = c1i * 512;  // u16 index of chunk base

  auto stageHi = [&](int b, size_t ko) {
    gl_lds16(Ahi + sA0 + ko, &lAh[b][cw0]);
    gl_lds16(Ahi + sA1 + ko, &lAh[b][cw1]);
    gl_lds16(Bhi + sB0 + ko, &lBh[b][cw0]);
    gl_lds16(Bhi + sB1 + ko, &lBh[b][cw1]);
  };
  auto stageLo = [&](int b, size_t ko) {
    gl_lds16(Alo + sA0 + ko, &lAl[b][cw0]);
    gl_lds16(Alo + sA1 + ko, &lAl[b][cw1]);
    gl_lds16(Blo + sB0 + ko, &lBl[b][cw0]);
    gl_lds16(Blo + sB1 + ko, &lBl[b][cw1]);
  };

  // ---- frag read offsets (un-swizzled): 2-way max bank aliasing (free).
  const int frow = lane & 15, kgrp = lane >> 4;
  const int wr = w >> 2, wc = w & 3;  // 2M x 4N waves; per-wave out 128x64
  int aoff[8], boff[4];
#pragma unroll
  for (int i = 0; i < 8; ++i) {
    int r = wr * 128 + i * 16 + frow;
    aoff[i] = r * 32 + ((kgrp + (r >> 1)) & 3) * 8;
  }
#pragma unroll
  for (int j = 0; j < 4; ++j) {
    int r = wc * 64 + j * 16 + frow;
    boff[j] = r * 32 + ((kgrp + (r >> 1)) & 3) * 8;
  }

  f32x4 acc[8][4];
#pragma unroll
  for (int i = 0; i < 8; ++i)
#pragma unroll
    for (int j = 0; j < 4; ++j) acc[i][j] = (f32x4){0.f, 0.f, 0.f, 0.f};

  // ---- prologue: stage kt0 (hi then lo); wait own hi; barrier.
  stageHi(0, 0);
  stageLo(0, 0);
  VM4BAR();

  bf16x8 ah[8], al[8], bh[4], bl[4];

  for (int kt = 0; kt < 63; ++kt) {
    const int p = kt & 1, q = p ^ 1;
    const size_t ko = (size_t)(kt + 1) * 32;
    // ---- phase A (hi*hi): read 12 frags, prefetch next hi, barrier, MFMA.
#pragma unroll
    for (int i = 0; i < 8; ++i) ah[i] = *(const bf16x8*)&lAh[p][aoff[i]];
#pragma unroll
    for (int j = 0; j < 4; ++j) bh[j] = *(const bf16x8*)&lBh[p][boff[j]];
    stageHi(q, ko);
    BAR();
    __builtin_amdgcn_s_setprio(1);
#pragma unroll
    for (int i = 0; i < 8; ++i)
#pragma unroll
      for (int j = 0; j < 4; ++j)
        acc[i][j] = __builtin_amdgcn_mfma_f32_16x16x32_bf16(ah[i], bh[j], acc[i][j], 0, 0, 0);
    __builtin_amdgcn_s_setprio(0);
    VM4BAR();  // ensures this tile's lo-planes (oldest 4) have landed

    // ---- phase B (hi*lo): read 4 frags, prefetch next lo, barrier, MFMA.
#pragma unroll
    for (int j = 0; j < 4; ++j) bl[j] = *(const bf16x8*)&lBl[p][boff[j]];
    stageLo(q, ko);
    BAR();
    __builtin_amdgcn_s_setprio(1);
#pragma unroll
    for (int i = 0; i < 8; ++i)
#pragma unroll
      for (int j = 0; j < 4; ++j)
        acc[i][j] = __builtin_amdgcn_mfma_f32_16x16x32_bf16(ah[i], bl[j], acc[i][j], 0, 0, 0);
    __builtin_amdgcn_s_setprio(0);
    BAR();

    // ---- phase C (lo*hi): read 8 frags, barrier, MFMA, wait next hi.
#pragma unroll
    for (int i = 0; i < 8; ++i) al[i] = *(const bf16x8*)&lAl[p][aoff[i]];
    BAR();
    __builtin_amdgcn_s_setprio(1);
#pragma unroll
    for (int i = 0; i < 8; ++i)
#pragma unroll
      for (int j = 0; j < 4; ++j)
        acc[i][j] = __builtin_amdgcn_mfma_f32_16x16x32_bf16(al[i], bh[j], acc[i][j], 0, 0, 0);
    __builtin_amdgcn_s_setprio(0);
    VM4BAR();  // ensures next tile's hi-planes (oldest 4) have landed
  }

  // ---- epilogue tile kt=63 (buf 1): drain remaining lo loads, no prefetch.
  VM0BAR();
  {
    const int p = 1;
#pragma unroll
    for (int i = 0; i < 8; ++i) ah[i] = *(const bf16x8*)&lAh[p][aoff[i]];
#pragma unroll
    for (int j = 0; j < 4; ++j) bh[j] = *(const bf16x8*)&lBh[p][boff[j]];
#pragma unroll
    for (int j = 0; j < 4; ++j) bl[j] = *(const bf16x8*)&lBl[p][boff[j]];
#pragma unroll
    for (int i = 0; i < 8; ++i) al[i] = *(const bf16x8*)&lAl[p][aoff[i]];
#pragma unroll
    for (int i = 0; i < 8; ++i)
#pragma unroll
      for (int j = 0; j < 4; ++j) {
        acc[i][j] = __builtin_amdgcn_mfma_f32_16x16x32_bf16(ah[i], bh[j], acc[i][j], 0, 0, 0);
        acc[i][j] = __builtin_amdgcn_mfma_f32_16x16x32_bf16(ah[i], bl[j], acc[i][j], 0, 0, 0);
        acc[i][j] = __builtin_amdgcn_mfma_f32_16x16x32_bf16(al[i], bh[j], acc[i][j], 0, 0, 0);
      }
  }

  // ---- C-write: C/D layout col=lane&15, row=(lane>>4)*4+reg  [m89-verified]
#pragma unroll
  for (int i = 0; i < 8; ++i) {
    const int gmb = m0 + wr * 128 + i * 16 + kgrp * 4;
#pragma unroll
    for (int j = 0; j < 4; ++j) {
      const int gn = n0 + wc * 64 + j * 16 + frow;
#pragma unroll
      for (int r = 0; r < 4; ++r) {
        float v = acc[i][j][r];
        const int gm = gmb + r;
        if constexpr (EPI2) {
          v += proj0[(size_t)(gm >> 3) * 16384 + gn];  // b = gm>>3
          v = v > 0.f ? v : v * LRELU_ALPHA;
        }
        C[(size_t)gm * 16384 + gn] = v;
      }
    }
  }
}

// -------------------- e = Wh·att_w ; softmax over s (8) --------------------
__global__ __launch_bounds__(256) void esoftmax_kernel(
    const float* __restrict__ Wh, const float* __restrict__ att_w,
    float* __restrict__ attn) {
  int bid = blockIdx.x;          // B*H = 2048 blocks
  int b = bid >> 3, h = bid & 7;
  int tid = threadIdx.x, lane = tid & 63, w = tid >> 6;
  __shared__ float ev[8];
  const float* aw = att_w + h * 2048;
#pragma unroll
  for (int si = 0; si < 2; ++si) {
    int s = w * 2 + si;
    const float* row = Wh + (size_t)((b * 8 + s) * 8 + h) * 2048;
    float sum = 0.f;
#pragma unroll
    for (int i = 0; i < 8; ++i) {
      int idx = (i * 64 + lane) * 4;
      f32x4 rv = *(const f32x4*)&row[idx];
      f32x4 av = *(const f32x4*)&aw[idx];
      sum += rv[0] * av[0] + rv[1] * av[1] + rv[2] * av[2] + rv[3] * av[3];
    }
#pragma unroll
    for (int off = 32; off > 0; off >>= 1) sum += __shfl_down(sum, off, 64);
    if (lane == 0) ev[s] = sum;
  }
  __syncthreads();
  if (tid == 0) {
    float mx = ev[0];
#pragma unroll
    for (int s = 1; s < 8; ++s) mx = fmaxf(mx, ev[s]);
    float ex[8], den = 0.f;
#pragma unroll
    for (int s = 0; s < 8; ++s) { ex[s] = expf(ev[s] - mx); den += ex[s]; }
    float inv = 1.f / den;
#pragma unroll
    for (int s = 0; s < 8; ++s) attn[b * 64 + h * 8 + s] = ex[s] * inv;
  }
}

// -------------------- out = x + (1/8) SUM_h (attn*Wh + bias) --------------------
__global__ __launch_bounds__(256) void out_kernel(
    const float* __restrict__ X, const float* __restrict__ bias,
    const float* __restrict__ Wh, const float* __restrict__ attn,
    float* __restrict__ out) {
  int bid = blockIdx.x;          // 2048 rows x 2 halves
  int m = bid >> 1;
  int half = bid & 1;
  int b = m >> 3, s = m & 7;
  int f0 = half * 1024 + threadIdx.x * 4;
  __shared__ float a_sm[8];
  if (threadIdx.x < 8) a_sm[threadIdx.x] = attn[b * 64 + threadIdx.x * 8 + s];
  __syncthreads();
  f32x4 acc = *(const f32x4*)&X[(size_t)m * 2048 + f0];
  f32x4 hs = {0.f, 0.f, 0.f, 0.f};
#pragma unroll
  for (int h = 0; h < 8; ++h) {
    f32x4 wv = *(const f32x4*)&Wh[(size_t)m * 16384 + h * 2048 + f0];
    f32x4 bv = *(const f32x4*)&bias[h * 2048 + f0];
    hs += wv * a_sm[h] + bv;
  }
  acc += hs * 0.125f;
  *(f32x4*)&out[(size_t)m * 2048 + f0] = acc;
}

extern "C" void kernel_launch(void* const* d_in, const int* in_sizes, int n_in,
                              void* d_out, int out_size, void* d_ws, size_t ws_size,
                              hipStream_t stream) {
  const float* X = (const float*)d_in[0];       // [256][8][2048]
  const float* W = (const float*)d_in[1];       // [8][4096][2048]
  const float* att_w = (const float*)d_in[2];   // [8][2048]
  const float* bias = (const float*)d_in[3];    // [8][2048]
  float* out = (float*)d_out;

  char* ws = (char*)d_ws;                       // 436,273,152 B used
  u16* Whi = (u16*)ws;                          // 134,217,728
  u16* Wlo = (u16*)(ws + 134217728ull);         // 134,217,728
  u16* Xhi = (u16*)(ws + 268435456ull);         //   8,388,608
  u16* Xlo = (u16*)(ws + 276824064ull);         //   8,388,608
  float* proj0 = (float*)(ws + 285212672ull);   //  16,777,216  [256][16384]
  float* Wh = (float*)(ws + 301989888ull);      // 134,217,728  [2048][16384]
  float* attn = (float*)(ws + 436207616ull);    //      65,536  [256][8][8]

  split_x_kernel<<<4096, 256, 0, stream>>>(X, Xhi, Xlo);
  transpose_split_w<<<16384, 256, 0, stream>>>(W, Whi, Wlo);
  // GEMM1: rows are X[b,0,:] -> A row stride = 8*2048, M=256, k offset 0 (W1)
  gemm3p<16384, false><<<64, 512, 0, stream>>>(Xhi, Xlo, Whi, Wlo, nullptr, proj0, 256, 0);
  // GEMM2: all (b,s) rows -> stride 2048, M=2048, k offset 2048 (W2)
  gemm3p<2048, true><<<512, 512, 0, stream>>>(Xhi, Xlo, Whi, Wlo, proj0, Wh, 2048, 2048);
  esoftmax_kernel<<<2048, 256, 0, stream>>>(Wh, att_w, attn);
  out_kernel<<<4096, 256, 0, stream>>>(X, bias, Wh, attn, out);
}

// Round 7
// 873.509 us; speedup vs baseline: 1.1293x; 1.1060x over previous
//
#include <hip/hip_runtime.h>
#include <stdint.h>

// GATv2 self-attention, MI355X/gfx950.  B=256 S=8 F=2048 H=8. fp32 in/out.
// GEMMs via bf16 hi/lo round-split 3-pass MFMA (hh+hl+lh, ~1e-5 accurate --
// R1/R2-validated numerics: hi = rn16(x), lo = rn16(x - hi)).
//
// Structure (R3): fast 256B/256B transpose, 2-phase GEMM schedule (T2/T3/T4/T5),
// GEMM1 at 128x256 tile, e-dot fused into GEMM2 epilogue (atomicAdd),
// softmax folded into out_kernel.

typedef __attribute__((ext_vector_type(4))) float f32x4;
typedef __attribute__((ext_vector_type(8))) short bf16x8;
typedef __attribute__((ext_vector_type(4))) unsigned short u16x4;
typedef unsigned short u16;
typedef unsigned int u32;

#define LRELU_ALPHA 0.3f

// Round-split (validated R1/R2): hi = rn16(x); lo = rn16(x - hi).
// |x-(hi+lo)| <= 2^-16|x|; dropped lo*lo GEMM term ~2^-16 rel.
struct HL { u16 h, l; };
__device__ __forceinline__ u16 bf16_rn(float x) {
  u32 u = __float_as_uint(x);
  u32 r = 0x7FFFu + ((u >> 16) & 1u);
  return (u16)((u + r) >> 16);
}
__device__ __forceinline__ HL split_rn(float x) {
  HL r;
  r.h = bf16_rn(x);
  float hv = __uint_as_float(((u32)r.h) << 16);
  r.l = bf16_rn(x - hv);
  return r;
}

// -------------------- prep: X fp32 -> hi/lo bf16 --------------------
__global__ __launch_bounds__(256) void split_x_kernel(
    const float* __restrict__ X, u16* __restrict__ Xhi, u16* __restrict__ Xlo) {
  int idx = (blockIdx.x * 256 + threadIdx.x) * 4;
  f32x4 v = *(const f32x4*)&X[idx];
  u16x4 hi, lo;
#pragma unroll
  for (int j = 0; j < 4; ++j) {
    HL r = split_rn(v[j]);
    hi[j] = r.h;
    lo[j] = r.l;
  }
  *(u16x4*)&Xhi[idx] = hi;
  *(u16x4*)&Xlo[idx] = lo;
}

// ---------- prep: W [h][c=4096][f=2048] fp32 -> [h][f][c] hi/lo bf16 ----------
// Tile [c=128][f=64]; 256B-contiguous global reads AND writes; f-major LDS so
// the transposed read is a conflict-free ds_read_b128. ct fastest in bid ->
// consecutive blocks stream adjacent c on both sides.
__global__ __launch_bounds__(256) void transpose_split_w(
    const float* __restrict__ W, u16* __restrict__ Whi, u16* __restrict__ Wlo) {
  __shared__ float tile[64][132];  // f-major; stride 132 keeps b128 reads 2-way
  const int bid = blockIdx.x;      // 8192 = 8h x 32ft x 32ct (ct fastest)
  const int ct = bid & 31;
  const int ft = (bid >> 5) & 31;
  const int h = bid >> 10;
  const int c0 = ct << 7, f0 = ft << 6;
  const int tid = threadIdx.x;

  // read: 128 c-rows x 256B (64 f); scalar-transpose into LDS (8-way stores, ok)
  {
    const int fo = (tid & 15) * 4;
    const int crb = tid >> 4;
    const float* src = W + ((size_t)(h * 4096 + c0) * 2048) + f0 + fo;
#pragma unroll
    for (int it = 0; it < 8; ++it) {
      const int cr = it * 16 + crb;
      f32x4 v = *(const f32x4*)&src[(size_t)cr * 2048];
#pragma unroll
      for (int j = 0; j < 4; ++j) tile[fo + j][cr] = v[j];
    }
  }
  __syncthreads();
  // write: 64 f-rows x 128 c; b128 LDS read (free), 256B global stores x2 planes
  {
    const int c4 = (tid & 31) * 4;
    const int flb = tid >> 5;
    const size_t dbase = (size_t)(h * 2048 + f0) * 4096 + c0 + c4;
#pragma unroll
    for (int it = 0; it < 8; ++it) {
      const int fl = it * 8 + flb;
      f32x4 v = *(const f32x4*)&tile[fl][c4];
      u16x4 hi, lo;
#pragma unroll
      for (int j = 0; j < 4; ++j) {
        HL r = split_rn(v[j]);
        hi[j] = r.h;
        lo[j] = r.l;
      }
      *(u16x4*)&Whi[dbase + (size_t)fl * 4096] = hi;
      *(u16x4*)&Wlo[dbase + (size_t)fl * 4096] = lo;
    }
  }
}

// -------------------- GEMM: NTILE=256, MTILE=WM*32, BK=32, 2-phase --------------------
__device__ __forceinline__ void gl_lds16(const u16* g, u16* l) {
  __builtin_amdgcn_global_load_lds(
      (const __attribute__((address_space(1))) void*)g,
      (__attribute__((address_space(3))) void*)l, 16, 0, 0);
}

template <int N> __device__ __forceinline__ void vm_bar();
template <> __device__ __forceinline__ void vm_bar<4>() {
  asm volatile("s_waitcnt vmcnt(4)\n\ts_barrier" ::: "memory");
}
template <> __device__ __forceinline__ void vm_bar<3>() {
  asm volatile("s_waitcnt vmcnt(3)\n\ts_barrier" ::: "memory");
}
template <> __device__ __forceinline__ void vm_bar<0>() {
  asm volatile("s_waitcnt vmcnt(0)\n\ts_barrier" ::: "memory");
}
#define BAR() asm volatile("s_barrier" ::: "memory")

// A: [M][AST] bf16 planes (X hi/lo). B: [N][4096] (transposed W), k-offset koff.
// EPI2: C = leaky(acc + proj0[gm>>3][gn]); fused e-dot: atomicAdd partial
// sum(v*att_w) into e[b*64 + h*8 + s].
template <int AST, bool EPI2, int WM>
__global__ __launch_bounds__(512, 2) void gemm2p(
    const u16* __restrict__ Ahi, const u16* __restrict__ Alo,
    const u16* __restrict__ Bhi, const u16* __restrict__ Blo,
    const float* __restrict__ proj0, float* __restrict__ C,
    const float* __restrict__ att_w, float* __restrict__ e,
    int Mdim, int koff) {
  constexpr int VMN = WM / 4 + 2;  // gl_lds per wave per stage (A + 2 B)
  __shared__ alignas(16) u16 lAh[2][WM * 1024];
  __shared__ alignas(16) u16 lAl[2][WM * 1024];
  __shared__ alignas(16) u16 lBh[2][8192];
  __shared__ alignas(16) u16 lBl[2][8192];

  const int tid = threadIdx.x;
  const int lane = tid & 63;
  const int w = tid >> 6;

  // XCD-bijective swizzle (grids % 8 == 0); mt fastest within nt.
  const int nwg = gridDim.x;
  const int bid = blockIdx.x;
  const int wg = (bid & 7) * (nwg >> 3) + (bid >> 3);
  const int MT = Mdim / (WM * 32);
  const int nt = wg / MT;
  const int mt = wg - nt * MT;
  const int m0 = mt * (WM * 32), n0 = nt << 8;

  // ---- staging: chunks of 1KiB (16 rows x 64B). B: 16 chunks, waves own 2.
  // A: WM*2 chunks, waves own WM/4. gl_lds dest linear; swizzle (phys 16B-unit
  // = (log + (row>>1)) & 3) applied via the GLOBAL source address.
  const int rB0 = w * 32 + (lane >> 2);
  const int rB1 = rB0 + 16;
  const int ulB0 = ((lane & 3) - (rB0 >> 1)) & 3;
  const int ulB1 = ((lane & 3) - (rB1 >> 1)) & 3;
  const size_t sB0 = (size_t)(n0 + rB0) * 4096 + (size_t)koff + ulB0 * 8;
  const size_t sB1 = (size_t)(n0 + rB1) * 4096 + (size_t)koff + ulB1 * 8;
  const int cwB0 = w * 1024, cwB1 = cwB0 + 512;

  const int rA0 = (WM == 8) ? (w * 32 + (lane >> 2)) : (w * 16 + (lane >> 2));
  const int rA1 = rA0 + 16;  // used only when WM==8
  const int ulA0 = ((lane & 3) - (rA0 >> 1)) & 3;
  const int ulA1 = ((lane & 3) - (rA1 >> 1)) & 3;
  const size_t sA0 = (size_t)(m0 + rA0) * AST + ulA0 * 8;
  const size_t sA1 = (size_t)(m0 + rA1) * AST + ulA1 * 8;
  const int cwA0 = (WM == 8) ? (w * 1024) : (w * 512);
  const int cwA1 = cwA0 + 512;

  auto stageHi = [&](int b, size_t ko) {
    gl_lds16(Ahi + sA0 + ko, &lAh[b][cwA0]);
    if constexpr (WM == 8) gl_lds16(Ahi + sA1 + ko, &lAh[b][cwA1]);
    gl_lds16(Bhi + sB0 + ko, &lBh[b][cwB0]);
    gl_lds16(Bhi + sB1 + ko, &lBh[b][cwB1]);
  };
  auto stageLo = [&](int b, size_t ko) {
    gl_lds16(Alo + sA0 + ko, &lAl[b][cwA0]);
    if constexpr (WM == 8) gl_lds16(Alo + sA1 + ko, &lAl[b][cwA1]);
    gl_lds16(Blo + sB0 + ko, &lBl[b][cwB0]);
    gl_lds16(Blo + sB1 + ko, &lBl[b][cwB1]);
  };

  // ---- frag read offsets (un-swizzle): 2-way max aliasing (free).
  const int frow = lane & 15, kgrp = lane >> 4;
  const int wr = w >> 2, wc = w & 3;  // 2M x 4N waves
  int aoff[WM], boff[4];
#pragma unroll
  for (int i = 0; i < WM; ++i) {
    int r = wr * (WM * 16) + i * 16 + frow;
    aoff[i] = r * 32 + ((kgrp + (r >> 1)) & 3) * 8;
  }
#pragma unroll
  for (int j = 0; j < 4; ++j) {
    int r = wc * 64 + j * 16 + frow;
    boff[j] = r * 32 + ((kgrp + (r >> 1)) & 3) * 8;
  }

  f32x4 acc[WM][4];
#pragma unroll
  for (int i = 0; i < WM; ++i)
#pragma unroll
    for (int j = 0; j < 4; ++j) acc[i][j] = (f32x4){0.f, 0.f, 0.f, 0.f};

  // ---- prologue: stage kt0 hi+lo; wait own hi (oldest VMN); barrier.
  stageHi(0, 0);
  stageLo(0, 0);
  vm_bar<VMN>();

  bf16x8 ah[WM], al[WM], bh[4], bl[4];

  for (int kt = 0; kt < 63; ++kt) {
    const int p = kt & 1, q = p ^ 1;
    const size_t ko = (size_t)(kt + 1) * 32;
    // phase A (hh): read hi frags, prefetch next hi, barrier, MFMA, wait cur lo.
#pragma unroll
    for (int i = 0; i < WM; ++i) ah[i] = *(const bf16x8*)&lAh[p][aoff[i]];
#pragma unroll
    for (int j = 0; j < 4; ++j) bh[j] = *(const bf16x8*)&lBh[p][boff[j]];
    stageHi(q, ko);
    BAR();
    __builtin_amdgcn_s_setprio(1);
#pragma unroll
    for (int i = 0; i < WM; ++i)
#pragma unroll
      for (int j = 0; j < 4; ++j)
        acc[i][j] = __builtin_amdgcn_mfma_f32_16x16x32_bf16(ah[i], bh[j], acc[i][j], 0, 0, 0);
    __builtin_amdgcn_s_setprio(0);
    vm_bar<VMN>();  // cur-tile lo planes landed

    // phase B (hl+lh): read lo frags, prefetch next lo, barrier, 2x MFMA, wait next hi.
#pragma unroll
    for (int j = 0; j < 4; ++j) bl[j] = *(const bf16x8*)&lBl[p][boff[j]];
#pragma unroll
    for (int i = 0; i < WM; ++i) al[i] = *(const bf16x8*)&lAl[p][aoff[i]];
    stageLo(q, ko);
    BAR();
    __builtin_amdgcn_s_setprio(1);
#pragma unroll
    for (int i = 0; i < WM; ++i)
#pragma unroll
      for (int j = 0; j < 4; ++j)
        acc[i][j] = __builtin_amdgcn_mfma_f32_16x16x32_bf16(ah[i], bl[j], acc[i][j], 0, 0, 0);
#pragma unroll
    for (int i = 0; i < WM; ++i)
#pragma unroll
      for (int j = 0; j < 4; ++j)
        acc[i][j] = __builtin_amdgcn_mfma_f32_16x16x32_bf16(al[i], bh[j], acc[i][j], 0, 0, 0);
    __builtin_amdgcn_s_setprio(0);
    vm_bar<VMN>();  // next-tile hi planes landed
  }

  // ---- tail tile kt=63 (buf 1): drain all, 3-pass.
  vm_bar<0>();
  {
    const int p = 1;
#pragma unroll
    for (int i = 0; i < WM; ++i) ah[i] = *(const bf16x8*)&lAh[p][aoff[i]];
#pragma unroll
    for (int j = 0; j < 4; ++j) bh[j] = *(const bf16x8*)&lBh[p][boff[j]];
#pragma unroll
    for (int j = 0; j < 4; ++j) bl[j] = *(const bf16x8*)&lBl[p][boff[j]];
#pragma unroll
    for (int i = 0; i < WM; ++i) al[i] = *(const bf16x8*)&lAl[p][aoff[i]];
#pragma unroll
    for (int i = 0; i < WM; ++i)
#pragma unroll
      for (int j = 0; j < 4; ++j) {
        acc[i][j] = __builtin_amdgcn_mfma_f32_16x16x32_bf16(ah[i], bh[j], acc[i][j], 0, 0, 0);
        acc[i][j] = __builtin_amdgcn_mfma_f32_16x16x32_bf16(ah[i], bl[j], acc[i][j], 0, 0, 0);
        acc[i][j] = __builtin_amdgcn_mfma_f32_16x16x32_bf16(al[i], bh[j], acc[i][j], 0, 0, 0);
      }
  }

  // ---- epilogue. C/D layout: col=lane&15, row=(lane>>4)*4+reg [m89-verified].
  float aw0, aw1, aw2, aw3;
  if constexpr (EPI2) {
    aw0 = att_w[n0 + wc * 64 + 0 * 16 + frow];
    aw1 = att_w[n0 + wc * 64 + 1 * 16 + frow];
    aw2 = att_w[n0 + wc * 64 + 2 * 16 + frow];
    aw3 = att_w[n0 + wc * 64 + 3 * 16 + frow];
  }
#pragma unroll
  for (int i = 0; i < WM; ++i) {
    const int gmb = m0 + wr * (WM * 16) + i * 16 + kgrp * 4;
    float vv[4][4];
#pragma unroll
    for (int j = 0; j < 4; ++j) {
      const int gn = n0 + wc * 64 + j * 16 + frow;
#pragma unroll
      for (int r = 0; r < 4; ++r) {
        float v = acc[i][j][r];
        if constexpr (EPI2) {
          v += proj0[(size_t)((gmb + r) >> 3) * 16384 + gn];  // b = gm>>3
          v = v > 0.f ? v : v * LRELU_ALPHA;
        }
        vv[j][r] = v;
        C[(size_t)(gmb + r) * 16384 + gn] = v;
      }
    }
    if constexpr (EPI2) {  // partial e[b,h,s] = sum_f v*att_w  (16-lane reduce)
#pragma unroll
      for (int r = 0; r < 4; ++r) {
        float psum = vv[0][r] * aw0 + vv[1][r] * aw1 + vv[2][r] * aw2 + vv[3][r] * aw3;
        psum += __shfl_xor(psum, 1, 16);
        psum += __shfl_xor(psum, 2, 16);
        psum += __shfl_xor(psum, 4, 16);
        psum += __shfl_xor(psum, 8, 16);
        if ((lane & 15) == 0) {
          const int gm = gmb + r;
          atomicAdd(&e[(gm >> 3) * 64 + (n0 >> 11) * 8 + (gm & 7)], psum);
        }
      }
    }
  }
}

// ------ out = x + (1/8) SUM_h (softmax(e)*Wh + bias); softmax fused ------
__global__ __launch_bounds__(256) void out_kernel(
    const float* __restrict__ X, const float* __restrict__ bias,
    const float* __restrict__ Wh, const float* __restrict__ e,
    float* __restrict__ out) {
  int bid = blockIdx.x;          // 2048 rows x 2 halves
  int m = bid >> 1;
  int half = bid & 1;
  int b = m >> 3, s = m & 7;
  int tid = threadIdx.x;
  __shared__ float a_sm[8];
  if (tid < 8) {                 // thread h: softmax over s, keep own-s value
    const float* eb = e + b * 64 + tid * 8;
    float ev[8];
#pragma unroll
    for (int k = 0; k < 8; ++k) ev[k] = eb[k];
    float mx = ev[0];
#pragma unroll
    for (int k = 1; k < 8; ++k) mx = fmaxf(mx, ev[k]);
    float den = 0.f;
#pragma unroll
    for (int k = 0; k < 8; ++k) den += expf(ev[k] - mx);
    a_sm[tid] = expf(ev[s] - mx) / den;
  }
  __syncthreads();
  int f0 = half * 1024 + tid * 4;
  f32x4 acc = *(const f32x4*)&X[(size_t)m * 2048 + f0];
  f32x4 hs = {0.f, 0.f, 0.f, 0.f};
#pragma unroll
  for (int h = 0; h < 8; ++h) {
    f32x4 wv = *(const f32x4*)&Wh[(size_t)m * 16384 + h * 2048 + f0];
    f32x4 bv = *(const f32x4*)&bias[h * 2048 + f0];
    hs += wv * a_sm[h] + bv;
  }
  acc += hs * 0.125f;
  *(f32x4*)&out[(size_t)m * 2048 + f0] = acc;
}

extern "C" void kernel_launch(void* const* d_in, const int* in_sizes, int n_in,
                              void* d_out, int out_size, void* d_ws, size_t ws_size,
                              hipStream_t stream) {
  const float* X = (const float*)d_in[0];       // [256][8][2048]
  const float* W = (const float*)d_in[1];       // [8][4096][2048]
  const float* att_w = (const float*)d_in[2];   // [8][2048] (flat = n-index)
  const float* bias = (const float*)d_in[3];    // [8][2048]
  float* out = (float*)d_out;

  char* ws = (char*)d_ws;                       // 436,273,152 B used
  u16* Whi = (u16*)ws;                          // 134,217,728
  u16* Wlo = (u16*)(ws + 134217728ull);         // 134,217,728
  u16* Xhi = (u16*)(ws + 268435456ull);         //   8,388,608
  u16* Xlo = (u16*)(ws + 276824064ull);         //   8,388,608
  float* proj0 = (float*)(ws + 285212672ull);   //  16,777,216  [256][16384]
  float* Wh = (float*)(ws + 301989888ull);      // 134,217,728  [2048][16384]
  float* e = (float*)(ws + 436207616ull);       //      65,536  [256][8][8]

  split_x_kernel<<<4096, 256, 0, stream>>>(X, Xhi, Xlo);
  transpose_split_w<<<8192, 256, 0, stream>>>(W, Whi, Wlo);
  (void)hipMemsetAsync(e, 0, 65536, stream);    // e accumulated via atomics
  // GEMM1: A rows = X[b,0,:] (stride 16384), M=256, W1 (koff 0), 128x256 tile
  gemm2p<16384, false, 4><<<128, 512, 0, stream>>>(
      Xhi, Xlo, Whi, Wlo, nullptr, proj0, nullptr, nullptr, 256, 0);
  // GEMM2: all (b,s) rows (stride 2048), M=2048, W2 (koff 2048), 256x256 tile
  gemm2p<2048, true, 8><<<512, 512, 0, stream>>>(
      Xhi, Xlo, Whi, Wlo, proj0, Wh, att_w, e, 2048, 2048);
  out_kernel<<<4096, 256, 0, stream>>>(X, bias, Wh, e, out);
}